// Round 4
// baseline (320.131 us; speedup 1.0000x reference)
//
#include <hip/hip_runtime.h>
#include <hip/hip_fp16.h>

#define NN 50000
#define DD 128
#define NE 800000
#define BN_EPS 1e-5f
#define NBUCK 196           // ceil(NN/256): bucket = dst>>8, 256 nodes per bucket
#define TILE_A 4096         // edges per k_binA block

typedef _Float16 f16x8 __attribute__((ext_vector_type(8)));
typedef float f32x4 __attribute__((ext_vector_type(4)));

// ---------------- CSR build ----------------
__global__ void k_hist(const int* __restrict__ dst, int* __restrict__ cnt, int ne) {
    int i = blockIdx.x * blockDim.x + threadIdx.x;
    if (i < ne) atomicAdd(&cnt[dst[i]], 1);
}

__global__ __launch_bounds__(256) void k_bsum(const int* __restrict__ cnt,
                                              int* __restrict__ bsum, int n) {
    __shared__ int red[256];
    int i = blockIdx.x * 256 + threadIdx.x;
    int v = (i < n) ? cnt[i] : 0;
    red[threadIdx.x] = v;
    __syncthreads();
    for (int off = 128; off > 0; off >>= 1) {
        if (threadIdx.x < off) red[threadIdx.x] += red[threadIdx.x + off];
        __syncthreads();
    }
    if (threadIdx.x == 0) bsum[blockIdx.x] = red[0];
}

__global__ __launch_bounds__(256) void k_bscan(int* __restrict__ bsum, int nb) {
    __shared__ int sh[256];
    int t = threadIdx.x;
    sh[t] = (t < nb) ? bsum[t] : 0;
    __syncthreads();
    for (int off = 1; off < 256; off <<= 1) {
        int add = (t >= off) ? sh[t - off] : 0;
        __syncthreads();
        sh[t] += add;
        __syncthreads();
    }
    if (t < nb) bsum[t] = sh[t];
}

// per-node rowp/cursor/dinv; block 0 zeroes stat sums + Z banks.
// Also: per-bucket staging cursor init, and degree histogram (64 bins) for the
// degree-balanced node permutation used by k_agg.
__global__ __launch_bounds__(256) void k_rowp(const int* __restrict__ cnt,
                                              const int* __restrict__ bsum,
                                              int* __restrict__ rowp,
                                              int* __restrict__ cursor,
                                              int* __restrict__ bucketCur,
                                              float* __restrict__ dinv,
                                              float* __restrict__ sumsZ,
                                              int* __restrict__ dcnt, int n) {
    if (blockIdx.x == 0) {
        for (int i = threadIdx.x; i < 8256; i += 256) sumsZ[i] = 0.f;
    }
    __shared__ int sh[256];
    __shared__ int dh[64];
    int t = threadIdx.x;
    if (t < 64) dh[t] = 0;
    int i = blockIdx.x * 256 + t;
    int v = (i < n) ? cnt[i] : 0;
    sh[t] = v;
    __syncthreads();
    for (int off = 1; off < 256; off <<= 1) {
        int add = (t >= off) ? sh[t - off] : 0;
        __syncthreads();
        sh[t] += add;
        __syncthreads();
    }
    int base = (blockIdx.x > 0) ? bsum[blockIdx.x - 1] : 0;
    int excl = base + sh[t] - v;
    if (i < n) {
        rowp[i] = excl;
        cursor[i] = excl;
        dinv[i] = 1.0f / sqrtf((float)(v + 1));
        if ((i & 255) == 0) bucketCur[i >> 8] = excl;
        if (i == n - 1) rowp[n] = excl + v;
        atomicAdd(&dh[v > 63 ? 63 : v], 1);
    }
    __syncthreads();
    if (t < 64 && dh[t]) atomicAdd(&dcnt[t], dh[t]);
}

// degree-bin exclusive scan -> dcur (64 bins, one wave)
__global__ __launch_bounds__(64) void k_dscan(const int* __restrict__ dcnt,
                                              int* __restrict__ dcur) {
    __shared__ int sh[64];
    int t = threadIdx.x;
    sh[t] = dcnt[t];
    __syncthreads();
    for (int off = 1; off < 64; off <<= 1) {
        int add = (t >= off) ? sh[t - off] : 0;
        __syncthreads();
        sh[t] += add;
        __syncthreads();
    }
    dcur[t] = sh[t] - dcnt[t];
}

// counting-sort scatter: perm = node ids ordered by degree (binA-style LDS rank)
__global__ __launch_bounds__(256) void k_dperm(const int* __restrict__ cnt,
                                               int* __restrict__ dcur,
                                               int* __restrict__ perm, int n) {
    __shared__ int dh[64], db[64];
    int t = threadIdx.x;
    if (t < 64) dh[t] = 0;
    __syncthreads();
    int i = blockIdx.x * 256 + t;
    int b = 0;
    if (i < n) {
        int v = cnt[i];
        b = v > 63 ? 63 : v;
        atomicAdd(&dh[b], 1);
    }
    __syncthreads();
    if (t < 64) {
        db[t] = dh[t] ? atomicAdd(&dcur[t], dh[t]) : 0;
        dh[t] = 0;
    }
    __syncthreads();
    if (i < n) {
        int r = atomicAdd(&dh[b], 1);
        perm[db[b] + r] = i;
    }
}

// ---------------- phase A: coarse bucket binning (single-writer line runs) -------
__global__ __launch_bounds__(256) void k_binA(const int* __restrict__ src,
                                              const int* __restrict__ dst,
                                              const float* __restrict__ dinv,
                                              int* __restrict__ bucketCur,
                                              uint2* __restrict__ evS, int ne) {
    __shared__ int hcnt[NBUCK];
    __shared__ int hbase[NBUCK];
    int tid = threadIdx.x;
    for (int i = tid; i < NBUCK; i += 256) hcnt[i] = 0;
    __syncthreads();
    int base = blockIdx.x * TILE_A;
    int lim = ne - base;
    if (lim > TILE_A) lim = TILE_A;
    for (int i = tid; i < lim; i += 256) {
        int d = dst[base + i];
        atomicAdd(&hcnt[d >> 8], 1);
    }
    __syncthreads();
    for (int b = tid; b < NBUCK; b += 256) {
        hbase[b] = atomicAdd(&bucketCur[b], hcnt[b]);
        hcnt[b] = 0;
    }
    __syncthreads();
    for (int i = tid; i < lim; i += 256) {
        int d = dst[base + i];
        int s = src[base + i];
        int bk = d >> 8;
        int rank = atomicAdd(&hcnt[bk], 1);
        int pos = hbase[bk] + rank;
        unsigned short hv = __half_as_ushort(__float2half_rn(dinv[s]));
        evS[pos] = make_uint2((unsigned)s | ((unsigned)(d & 255) << 16),
                              (unsigned)hv);
    }
}

// ---------------- phase B: fine scatter within bucket (one block per bucket) -----
__global__ __launch_bounds__(256) void k_binB(const uint2* __restrict__ evS,
                                              const int* __restrict__ rowp,
                                              int* __restrict__ cursor,
                                              unsigned* __restrict__ ev, int n) {
    int b = blockIdx.x;
    int node0 = b << 8;
    int lo = rowp[node0];
    int nhi = node0 + 256;
    if (nhi > n) nhi = n;
    int hi = rowp[nhi];
    for (int p = lo + (int)threadIdx.x; p < hi; p += 256) {
        uint2 r = evS[p];
        int node = node0 + (int)(r.x >> 16);
        int pos = atomicAdd(&cursor[node], 1);
        ev[pos] = (r.x & 0xFFFFu) | (r.y << 16);
    }
}

// ---------------- W prep: fp16 B-fragment-linear layout for MFMA ----------------
__global__ __launch_bounds__(256) void k_wprep(const float* __restrict__ W1,
                                               const float* __restrict__ W2,
                                               __half* __restrict__ Wf) {
    int widx = blockIdx.x & 1;
    const float* W = widx ? W2 : W1;
    __half* outp = Wf + (size_t)widx * DD * DD;
    int s = (blockIdx.x >> 1) * 256 + threadIdx.x;   // 0..2047
    int l = s & 63;
    int ks = (s >> 6) & 3;
    int cb = s >> 8;
    int col = cb * 16 + (l & 15);
    int kbase = ks * 32 + (l >> 4) * 8;
    __align__(16) __half tmp[8];
    #pragma unroll
    for (int j = 0; j < 8; j++) tmp[j] = __float2half_rn(W[(kbase + j) * DD + col]);
    *(uint4*)(outp + s * 8) = *(uint4*)tmp;
}

// ---------------- GEMM: MFMA fp16, optional fused BN+ReLU+residual prologue ------
// Tile 64 rows x 128 cols, K=128.  4 waves, wave w owns rows [16w,16w+16).
// If res != nullptr: A-input is BN(Araw)*relu + res (layer-1 epilogue fused into
// layer-2 staging); the fp32 result is also written to Hout for the later
// residual/output path.  A staged fp16 fragment-linear, XOR-swizzled both sides.
#define GTILE 64
__global__ __launch_bounds__(256) void k_gemm(const float* __restrict__ A,
                                              const float* __restrict__ res,
                                              const float* __restrict__ sums,
                                              const float* __restrict__ gamma,
                                              const float* __restrict__ beta,
                                              float* __restrict__ Hout,
                                              const __half* __restrict__ Wf,
                                              __half* __restrict__ C, int n) {
    __shared__ __half sW[DD * DD];       // 32 KB fragment-linear (no swizzle)
    __shared__ __half sA[GTILE * DD];    // 16 KB fragment-linear (swizzled)
    __shared__ float s_scale[DD], s_shift[DD];
    int tid = threadIdx.x;
    int wave = tid >> 6;
    int lane = tid & 63;
    bool fused = (res != nullptr);

    {   // stage W fragments (linear copy)
        const float4* wg = (const float4*)Wf;
        float4* ws = (float4*)sW;
        for (int i = tid; i < DD * DD / 8; i += 256) ws[i] = wg[i];
    }
    if (fused && tid < DD) {
        float ssum = 0.f, qsum = 0.f;
        #pragma unroll
        for (int b = 0; b < 16; b++) {
            ssum += sums[b * 256 + tid];
            qsum += sums[b * 256 + 128 + tid];
        }
        float inv_n = 1.0f / (float)n;
        float mean = ssum * inv_n;
        float var = qsum * inv_n - mean * mean;
        float sc = gamma[tid] * (1.0f / sqrtf(var + BN_EPS));
        s_scale[tid] = sc;
        s_shift[tid] = beta[tid] - mean * sc;
    }

    int ntiles = (n + GTILE - 1) / GTILE;
    for (int t = blockIdx.x; t < ntiles; t += gridDim.x) {
        int row0 = t * GTILE;
        __syncthreads();   // covers W/stats stage (1st iter) + prev-tile reads
        {   // stage A tile: (optional BN+ReLU+res) fp32 -> fp16 fragments, swizzled
            const float4* Av = (const float4*)(A + (size_t)row0 * DD);
            const float4* Rv = (const float4*)(res + (size_t)row0 * DD);
            float4* Hv = (float4*)(Hout + (size_t)row0 * DD);
            for (int i = tid; i < GTILE * DD / 4; i += 256) {
                int r = i >> 5;         // row in tile
                int kq = i & 31;        // k = 4*kq
                bool rowok = (row0 + r < n);
                float4 v = make_float4(0.f, 0.f, 0.f, 0.f);
                if (rowok) v = Av[i];
                if (fused) {
                    float4 rv = make_float4(0.f, 0.f, 0.f, 0.f);
                    if (rowok) rv = Rv[i];
                    int f4 = kq * 4;
                    v.x = fmaxf(v.x * s_scale[f4]     + s_shift[f4],     0.f) + rv.x;
                    v.y = fmaxf(v.y * s_scale[f4 + 1] + s_shift[f4 + 1], 0.f) + rv.y;
                    v.z = fmaxf(v.z * s_scale[f4 + 2] + s_shift[f4 + 2], 0.f) + rv.z;
                    v.w = fmaxf(v.w * s_scale[f4 + 3] + s_shift[f4 + 3], 0.f) + rv.w;
                    if (rowok) Hv[i] = v;
                }
                __half2 p0 = __floats2half2_rn(v.x, v.y);
                __half2 p1 = __floats2half2_rn(v.z, v.w);
                uint2 pk;
                pk.x = *(unsigned*)&p0;
                pk.y = *(unsigned*)&p1;
                int slot = ((r >> 4) * 4 + (kq >> 3)) * 64 +
                           (((kq >> 1) & 3) << 4) + (r & 15);
                int byte = slot * 16 + (kq & 1) * 8;
                byte ^= ((byte >> 9) & 7) << 4;
                *(uint2*)((char*)sA + byte) = pk;
            }
        }
        __syncthreads();

        f32x4 acc[8];
        #pragma unroll
        for (int cb = 0; cb < 8; cb++) acc[cb] = (f32x4)(0.0f);
        f16x8 af[4];
        #pragma unroll
        for (int ks = 0; ks < 4; ks++) {
            int rb = ((wave * 4 + ks) * 64 + lane) * 16;
            rb ^= ((rb >> 9) & 7) << 4;
            af[ks] = *(const f16x8*)((const char*)sA + rb);
        }
        #pragma unroll
        for (int cb = 0; cb < 8; cb++) {
            #pragma unroll
            for (int ks = 0; ks < 4; ks++) {
                f16x8 bf = *(const f16x8*)(sW + ((cb * 4 + ks) * 64 + lane) * 8);
                acc[cb] = __builtin_amdgcn_mfma_f32_16x16x32_f16(af[ks], bf,
                                                                 acc[cb], 0, 0, 0);
            }
        }

        // epilogue: acc -> per-wave LDS region (col-xor spreads banks) -> coalesced
        __half* sC = sA + wave * (16 * DD);
        #pragma unroll
        for (int cb = 0; cb < 8; cb++) {
            int col = cb * 16 + (lane & 15);
            #pragma unroll
            for (int rr = 0; rr < 4; rr++) {
                int grow = (lane >> 4) * 4 + rr;
                sC[grow * DD + (col ^ ((grow & 3) << 4))] = __float2half(acc[cb][rr]);
            }
        }
        __syncthreads();
        #pragma unroll
        for (int i2 = 0; i2 < 4; i2++) {
            int o = (i2 * 64 + lane) * 8;   // half index in wave's 16x128 region
            int grow = o >> 7;
            int col0 = o & 127;
            int row = row0 + wave * 16 + grow;
            if (row < n) {
                uint4 val = *(uint4*)(sC + grow * DD + (col0 ^ ((grow & 3) << 4)));
                *(uint4*)(C + (size_t)row * DD + col0) = val;
            }
        }
    }
}

// ---------------- aggregation: 16 lanes/node, degree-sorted perm, fused BN stats --
// perm orders nodes by degree so the 4 nodes sharing a wave have ~equal edge
// counts (kills the max-of-4-Poisson divergence, ~26% masked-lane waste).
__global__ __launch_bounds__(256) void k_agg(const __half* __restrict__ h,
                                             const int* __restrict__ rowp,
                                             const unsigned* __restrict__ ev,
                                             const float* __restrict__ dinv,
                                             const int* __restrict__ perm,
                                             const float* __restrict__ bias,
                                             float* __restrict__ out,
                                             float* __restrict__ sums, int n) {
    int tid = threadIdx.x;
    int grp = tid >> 4;            // node slot within block 0..15
    int m = tid & 15;              // 16 B chunk within row
    int idx = blockIdx.x * 16 + grp;
    bool activ = idx < n;
    int node = activ ? perm[idx] : 0;

    int beg = 0, end = 0;
    float di = 0.f;
    if (activ) { beg = rowp[node]; end = rowp[node + 1]; di = dinv[node]; }

    float sf[8] = {0.f, 0.f, 0.f, 0.f, 0.f, 0.f, 0.f, 0.f};
    float bf[8];
    {
        float4 b0 = *(const float4*)(bias + m * 8);
        float4 b1 = *(const float4*)(bias + m * 8 + 4);
        bf[0] = b0.x; bf[1] = b0.y; bf[2] = b0.z; bf[3] = b0.w;
        bf[4] = b1.x; bf[5] = b1.y; bf[6] = b1.z; bf[7] = b1.w;
        if (activ) {
            float4 raw = *(const float4*)(h + (size_t)node * DD + m * 8);
            const __half2* hp = (const __half2*)&raw;
            float2 s0 = __half22float2(hp[0]);
            float2 s1 = __half22float2(hp[1]);
            float2 s2 = __half22float2(hp[2]);
            float2 s3 = __half22float2(hp[3]);
            sf[0] = s0.x; sf[1] = s0.y; sf[2] = s1.x; sf[3] = s1.y;
            sf[4] = s2.x; sf[5] = s2.y; sf[6] = s3.x; sf[7] = s3.y;
        }
    }

    float a[8] = {0.f, 0.f, 0.f, 0.f, 0.f, 0.f, 0.f, 0.f};
    #pragma unroll 4
    for (int e = beg; e < end; e++) {
        unsigned r = ev[e];
        int s = r & 0xFFFF;
        float ww = __half2float(__ushort_as_half((unsigned short)(r >> 16)));
        float4 raw = *(const float4*)(h + (size_t)s * DD + m * 8);
        const __half2* hp = (const __half2*)&raw;
        float2 c0 = __half22float2(hp[0]);
        float2 c1 = __half22float2(hp[1]);
        float2 c2 = __half22float2(hp[2]);
        float2 c3 = __half22float2(hp[3]);
        a[0] += ww * c0.x; a[1] += ww * c0.y;
        a[2] += ww * c1.x; a[3] += ww * c1.y;
        a[4] += ww * c2.x; a[5] += ww * c2.y;
        a[6] += ww * c3.x; a[7] += ww * c3.y;
    }

    float o[8];
    float dii = di * di;
    #pragma unroll
    for (int j = 0; j < 8; j++) o[j] = di * a[j] + dii * sf[j] + bf[j];
    if (activ) {
        float* op = out + (size_t)node * DD + m * 8;
        *(float4*)op = make_float4(o[0], o[1], o[2], o[3]);
        *(float4*)(op + 4) = make_float4(o[4], o[5], o[6], o[7]);
    }

    __shared__ float rs[16][132];            // +4 pad breaks 128-stride conflicts
    #pragma unroll
    for (int j = 0; j < 8; j++) rs[grp][m * 8 + j] = activ ? o[j] : 0.f;
    __syncthreads();

    int bank = blockIdx.x & 15;
    if (tid < 128) {
        float s = 0.f;
        #pragma unroll
        for (int r2 = 0; r2 < 16; r2++) s += rs[r2][tid];
        atomicAdd(&sums[bank * 256 + tid], s);
    } else {
        int f = tid - 128;
        float q = 0.f;
        #pragma unroll
        for (int r2 = 0; r2 < 16; r2++) { float v = rs[r2][f]; q += v * v; }
        atomicAdd(&sums[bank * 256 + 128 + f], q);
    }
}

// ---------------- BN apply + ReLU + residual + fused attention score (layer 2) ----
__global__ __launch_bounds__(256) void k_bn(const float* __restrict__ X,
                                            const float* __restrict__ res,
                                            const float* __restrict__ sums,
                                            const float* __restrict__ gamma,
                                            const float* __restrict__ beta,
                                            const float* __restrict__ Wa,
                                            const float* __restrict__ ba,
                                            float* __restrict__ out,
                                            float* __restrict__ evec,
                                            float* __restrict__ Zb, int n) {
    __shared__ float s_scale[128], s_shift[128];
    if (threadIdx.x < 128) {
        int ff = threadIdx.x;
        float ssum = 0.f, qsum = 0.f;
        #pragma unroll
        for (int b = 0; b < 16; b++) {
            ssum += sums[b * 256 + ff];
            qsum += sums[b * 256 + 128 + ff];
        }
        float inv_n = 1.0f / (float)n;
        float mean = ssum * inv_n;
        float var = qsum * inv_n - mean * mean;
        float sc = gamma[ff] * (1.0f / sqrtf(var + BN_EPS));
        s_scale[ff] = sc;
        s_shift[ff] = beta[ff] - mean * sc;
    }
    __syncthreads();
    int idx = blockIdx.x * 256 + threadIdx.x;
    int total = n * (DD / 4);
    int f = (threadIdx.x & 31) * 4;
    float o[4] = {0.f, 0.f, 0.f, 0.f};
    if (idx < total) {
        float4 v = ((const float4*)X)[idx];
        float4 rv = ((const float4*)res)[idx];
        float vi[4] = {v.x, v.y, v.z, v.w};
        float ri[4] = {rv.x, rv.y, rv.z, rv.w};
        #pragma unroll
        for (int j = 0; j < 4; j++) {
            float x = vi[j] * s_scale[f + j] + s_shift[f + j];
            x = fmaxf(x, 0.f);
            o[j] = x + ri[j];
        }
        ((float4*)out)[idx] = make_float4(o[0], o[1], o[2], o[3]);
    }
    if (Wa != nullptr) {
        float t = 0.f;
        if (idx < total) {
            float4 wv = *(const float4*)(Wa + f);
            t = o[0] * wv.x + o[1] * wv.y + o[2] * wv.z + o[3] * wv.w;
        }
        #pragma unroll
        for (int m = 16; m >= 1; m >>= 1) t += __shfl_xor(t, m);
        __shared__ float part[8];
        if ((threadIdx.x & 31) == 0) {
            float ev = 0.f;
            if (idx < total) {
                ev = expf(tanhf(t + ba[0]));
                evec[idx >> 5] = ev;
            }
            part[threadIdx.x >> 5] = ev;
        }
        __syncthreads();
        if (threadIdx.x == 0) {
            float z = part[0] + part[1] + part[2] + part[3] +
                      part[4] + part[5] + part[6] + part[7];
            atomicAdd(&Zb[blockIdx.x & 63], z);
        }
    }
}

// ---------------- final: out = h * e / Z (Z from 64 banks) ----------------
__global__ __launch_bounds__(256) void k_out(const float* __restrict__ H,
                                             const float* __restrict__ evec,
                                             const float* __restrict__ Zb,
                                             float* __restrict__ out, int n) {
    __shared__ float sZ;
    if (threadIdx.x == 0) {
        float z = 0.f;
        #pragma unroll
        for (int i = 0; i < 64; i++) z += Zb[i];
        sZ = z;
    }
    __syncthreads();
    int idx = blockIdx.x * blockDim.x + threadIdx.x;
    int total = n * (DD / 4);
    if (idx >= total) return;
    int node = idx >> 5;
    float s = evec[node] / sZ;
    float4 h = ((const float4*)H)[idx];
    ((float4*)out)[idx] = make_float4(h.x * s, h.y * s, h.z * s, h.w * s);
}

extern "C" void kernel_launch(void* const* d_in, const int* in_sizes, int n_in,
                              void* d_out, int out_size, void* d_ws, size_t ws_size,
                              hipStream_t stream) {
    const float* x   = (const float*)d_in[0];
    const int* eidx  = (const int*)d_in[1];
    const float* W1  = (const float*)d_in[2];
    const float* b1  = (const float*)d_in[3];
    const float* g1  = (const float*)d_in[4];
    const float* be1 = (const float*)d_in[5];
    const float* W2  = (const float*)d_in[6];
    const float* b2  = (const float*)d_in[7];
    const float* g2  = (const float*)d_in[8];
    const float* be2 = (const float*)d_in[9];
    const float* Wa  = (const float*)d_in[10];
    const float* ba  = (const float*)d_in[11];
    float* out = (float*)d_out;

    const int* srcp = eidx;
    const int* dstp = eidx + NE;

    float* bufA = (float*)d_ws;              // N*D region; fp16 gather table
    float* bufB = bufA + (size_t)NN * DD;    // N*D (staging evS / agg out)
    float* bufC = bufB + (size_t)NN * DD;    // N*D (h1 / h2)
    unsigned* ev = (unsigned*)(bufC + (size_t)NN * DD);   // NE packed 4B records
    float* dinv = (float*)(ev + NE);         // NN
    float* evec = dinv + NN;                 // NN
    float* sums = evec + NN;                 // 2 layers x 16 banks x 256 = 8192
    float* Zb   = sums + 8192;               // 64 banks
    int* cnt    = (int*)(Zb + 64);           // NN
    int* dcnt   = cnt + NN;                  // 64 degree bins
    int* dcur   = dcnt + 64;                 // 64
    int* rowp   = dcur + 64;                 // NN+1 (pad 64)
    int* cursor = rowp + NN + 64;            // NN
    int* bsum   = cursor + NN;               // 256
    int* bucketCur = bsum + 256;             // NBUCK (pad 256)
    int* perm   = bucketCur + 256;           // NN (degree-sorted node order)
    __half* Wf  = (__half*)(perm + NN);      // 2 x DD*DD fp16 fragment tables

    __half* hH  = (__half*)bufA;             // fp16 gather table, 12.8 MB
    uint2* evS  = (uint2*)bufB;              // staged 8B records, 6.4 MB (aliased)

    float* sumsL1 = sums;
    float* sumsL2 = sums + 4096;

    const int nscan = (NN + 255) / 256;      // 196 blocks

    // ---- W fragment prep ----
    k_wprep<<<16, 256, 0, stream>>>(W1, W2, Wf);

    // ---- CSR build (k_rowp block 0 zeroes sums+Zb; memset covers cnt+dcnt) ----
    hipMemsetAsync(cnt, 0, (size_t)(NN + 64) * sizeof(int), stream);
    k_hist<<<(NE + 255) / 256, 256, 0, stream>>>(dstp, cnt, NE);
    k_bsum<<<nscan, 256, 0, stream>>>(cnt, bsum, NN);
    k_bscan<<<1, 256, 0, stream>>>(bsum, nscan);
    k_rowp<<<nscan, 256, 0, stream>>>(cnt, bsum, rowp, cursor, bucketCur, dinv,
                                      sums, dcnt, NN);
    k_binA<<<(NE + TILE_A - 1) / TILE_A, 256, 0, stream>>>(srcp, dstp, dinv,
                                                           bucketCur, evS, NE);
    k_binB<<<NBUCK, 256, 0, stream>>>(evS, rowp, cursor, ev, NN);
    k_dscan<<<1, 64, 0, stream>>>(dcnt, dcur);
    k_dperm<<<nscan, 256, 0, stream>>>(cnt, dcur, perm, NN);

    int gemm_grid = (NN + GTILE - 1) / GTILE;        // 782
    int agg_grid  = (NN + 15) / 16;                  // 3125
    int ew_grid   = (NN * (DD / 4) + 255) / 256;     // 6250

    // ---- layer 1 (plain GEMM from x) ----
    k_gemm<<<gemm_grid, 256, 0, stream>>>(x, nullptr, nullptr, nullptr, nullptr,
                                          nullptr, Wf, hH, NN);
    k_agg<<<agg_grid, 256, 0, stream>>>(hH, rowp, ev, dinv, perm, b1, bufB,
                                        sumsL1, NN);

    // ---- layer 2 (BN1+ReLU+residual fused into GEMM2 staging; writes h1->bufC) --
    k_gemm<<<gemm_grid, 256, 0, stream>>>(bufB, x, sumsL1, g1, be1, bufC,
                                          Wf + (size_t)DD * DD, hH, NN);
    k_agg<<<agg_grid, 256, 0, stream>>>(hH, rowp, ev, dinv, perm, b2, bufB,
                                        sumsL2, NN);
    k_bn<<<ew_grid, 256, 0, stream>>>(bufB, bufC, sumsL2, g2, be2, Wa, ba,
                                      bufC, evec, Zb, NN);   // in-place res ok

    // ---- output ----
    k_out<<<ew_grid, 256, 0, stream>>>(bufC, evec, Zb, out, NN);
}

// Round 5
// 315.893 us; speedup vs baseline: 1.0134x; 1.0134x over previous
//
#include <hip/hip_runtime.h>
#include <hip/hip_fp16.h>

#define NN 50000
#define DD 128
#define NE 800000
#define BN_EPS 1e-5f
#define NBUCK 196           // ceil(NN/256): bucket = dst>>8, 256 nodes per bucket
#define TILE_A 4096         // edges per k_binA block

typedef _Float16 f16x8 __attribute__((ext_vector_type(8)));
typedef float f32x4 __attribute__((ext_vector_type(4)));

// ---------------- CSR build ----------------
__global__ void k_hist(const int* __restrict__ dst, int* __restrict__ cnt, int ne) {
    int i = blockIdx.x * blockDim.x + threadIdx.x;
    if (i < ne) atomicAdd(&cnt[dst[i]], 1);
}

__global__ __launch_bounds__(256) void k_bsum(const int* __restrict__ cnt,
                                              int* __restrict__ bsum, int n) {
    __shared__ int red[256];
    int i = blockIdx.x * 256 + threadIdx.x;
    int v = (i < n) ? cnt[i] : 0;
    red[threadIdx.x] = v;
    __syncthreads();
    for (int off = 128; off > 0; off >>= 1) {
        if (threadIdx.x < off) red[threadIdx.x] += red[threadIdx.x + off];
        __syncthreads();
    }
    if (threadIdx.x == 0) bsum[blockIdx.x] = red[0];
}

__global__ __launch_bounds__(256) void k_bscan(int* __restrict__ bsum, int nb) {
    __shared__ int sh[256];
    int t = threadIdx.x;
    sh[t] = (t < nb) ? bsum[t] : 0;
    __syncthreads();
    for (int off = 1; off < 256; off <<= 1) {
        int add = (t >= off) ? sh[t - off] : 0;
        __syncthreads();
        sh[t] += add;
        __syncthreads();
    }
    if (t < nb) bsum[t] = sh[t];
}

// per-node rowp/cursor/dinv; block 0 zeroes stat sums + Z banks.
// Also initializes the per-bucket staging cursor (bucketCur[b] = rowp[b*256]).
__global__ __launch_bounds__(256) void k_rowp(const int* __restrict__ cnt,
                                              const int* __restrict__ bsum,
                                              int* __restrict__ rowp,
                                              int* __restrict__ cursor,
                                              int* __restrict__ bucketCur,
                                              float* __restrict__ dinv,
                                              float* __restrict__ sumsZ, int n) {
    if (blockIdx.x == 0) {
        for (int i = threadIdx.x; i < 8256; i += 256) sumsZ[i] = 0.f;
    }
    __shared__ int sh[256];
    int t = threadIdx.x;
    int i = blockIdx.x * 256 + t;
    int v = (i < n) ? cnt[i] : 0;
    sh[t] = v;
    __syncthreads();
    for (int off = 1; off < 256; off <<= 1) {
        int add = (t >= off) ? sh[t - off] : 0;
        __syncthreads();
        sh[t] += add;
        __syncthreads();
    }
    int base = (blockIdx.x > 0) ? bsum[blockIdx.x - 1] : 0;
    int excl = base + sh[t] - v;
    if (i < n) {
        rowp[i] = excl;
        cursor[i] = excl;
        dinv[i] = 1.0f / sqrtf((float)(v + 1));
        if ((i & 255) == 0) bucketCur[i >> 8] = excl;
        if (i == n - 1) rowp[n] = excl + v;
    }
}

// ---------------- phase A: coarse bucket binning (single-writer line runs) -------
// 4 B staged record: src (16 b) | dst-within-bucket (8 b).  The edge weight
// dinv[src] is gone — it is folded into the fp16 gather table at GEMM epilogue.
__global__ __launch_bounds__(256) void k_binA(const int* __restrict__ src,
                                              const int* __restrict__ dst,
                                              int* __restrict__ bucketCur,
                                              unsigned* __restrict__ evS, int ne) {
    __shared__ int hcnt[NBUCK];
    __shared__ int hbase[NBUCK];
    int tid = threadIdx.x;
    for (int i = tid; i < NBUCK; i += 256) hcnt[i] = 0;
    __syncthreads();
    int base = blockIdx.x * TILE_A;
    int lim = ne - base;
    if (lim > TILE_A) lim = TILE_A;
    for (int i = tid; i < lim; i += 256) {
        int d = dst[base + i];
        atomicAdd(&hcnt[d >> 8], 1);
    }
    __syncthreads();
    for (int b = tid; b < NBUCK; b += 256) {
        hbase[b] = atomicAdd(&bucketCur[b], hcnt[b]);
        hcnt[b] = 0;
    }
    __syncthreads();
    for (int i = tid; i < lim; i += 256) {
        int d = dst[base + i];
        int s = src[base + i];
        int bk = d >> 8;
        int rank = atomicAdd(&hcnt[bk], 1);
        evS[hbase[bk] + rank] = (unsigned)s | ((unsigned)(d & 255) << 16);
    }
}

// ---------------- phase B: fine scatter within bucket (one block per bucket) -----
__global__ __launch_bounds__(256) void k_binB(const unsigned* __restrict__ evS,
                                              const int* __restrict__ rowp,
                                              int* __restrict__ cursor,
                                              unsigned* __restrict__ ev, int n) {
    int b = blockIdx.x;
    int node0 = b << 8;
    int lo = rowp[node0];
    int nhi = node0 + 256;
    if (nhi > n) nhi = n;
    int hi = rowp[nhi];
    for (int p = lo + (int)threadIdx.x; p < hi; p += 256) {
        unsigned r = evS[p];
        int node = node0 + (int)(r >> 16);
        int pos = atomicAdd(&cursor[node], 1);
        ev[pos] = r & 0xFFFFu;
    }
}

// ---------------- W prep: fp16 B-fragment-linear layout for MFMA ----------------
__global__ __launch_bounds__(256) void k_wprep(const float* __restrict__ W1,
                                               const float* __restrict__ W2,
                                               __half* __restrict__ Wf) {
    int widx = blockIdx.x & 1;
    const float* W = widx ? W2 : W1;
    __half* outp = Wf + (size_t)widx * DD * DD;
    int s = (blockIdx.x >> 1) * 256 + threadIdx.x;   // 0..2047
    int l = s & 63;
    int ks = (s >> 6) & 3;
    int cb = s >> 8;
    int col = cb * 16 + (l & 15);
    int kbase = ks * 32 + (l >> 4) * 8;
    __align__(16) __half tmp[8];
    #pragma unroll
    for (int j = 0; j < 8; j++) tmp[j] = __float2half_rn(W[(kbase + j) * DD + col]);
    *(uint4*)(outp + s * 8) = *(uint4*)tmp;
}

// ---------------- GEMM: MFMA fp16, optional fused BN+ReLU+residual prologue ------
// Tile 64 rows x 128 cols, K=128.  4 waves, wave w owns rows [16w,16w+16).
// fp16 C table is scaled by dscale[row] (= dinv) so k_agg needs no edge weight.
// If res != nullptr: A-input is BN(Araw)+ReLU+res (layer-1 epilogue fused into
// layer-2 staging); the fp32 (unscaled) result also goes to Hout for the
// residual/output path.
#define GTILE 64
__global__ __launch_bounds__(256) void k_gemm(const float* __restrict__ A,
                                              const float* __restrict__ res,
                                              const float* __restrict__ sums,
                                              const float* __restrict__ gamma,
                                              const float* __restrict__ beta,
                                              float* __restrict__ Hout,
                                              const float* __restrict__ dscale,
                                              const __half* __restrict__ Wf,
                                              __half* __restrict__ C, int n) {
    __shared__ __half sW[DD * DD];       // 32 KB fragment-linear (no swizzle)
    __shared__ __half sA[GTILE * DD];    // 16 KB fragment-linear (swizzled)
    __shared__ float s_scale[DD], s_shift[DD];
    int tid = threadIdx.x;
    int wave = tid >> 6;
    int lane = tid & 63;
    bool fused = (res != nullptr);

    {   // stage W fragments (linear copy)
        const float4* wg = (const float4*)Wf;
        float4* ws = (float4*)sW;
        for (int i = tid; i < DD * DD / 8; i += 256) ws[i] = wg[i];
    }
    if (fused && tid < DD) {
        float ssum = 0.f, qsum = 0.f;
        #pragma unroll
        for (int b = 0; b < 16; b++) {
            ssum += sums[b * 256 + tid];
            qsum += sums[b * 256 + 128 + tid];
        }
        float inv_n = 1.0f / (float)n;
        float mean = ssum * inv_n;
        float var = qsum * inv_n - mean * mean;
        float sc = gamma[tid] * (1.0f / sqrtf(var + BN_EPS));
        s_scale[tid] = sc;
        s_shift[tid] = beta[tid] - mean * sc;
    }

    int ntiles = (n + GTILE - 1) / GTILE;
    for (int t = blockIdx.x; t < ntiles; t += gridDim.x) {
        int row0 = t * GTILE;
        __syncthreads();   // covers W/stats stage (1st iter) + prev-tile reads
        {   // stage A tile: (optional BN+ReLU+res) fp32 -> fp16 fragments, swizzled
            const float4* Av = (const float4*)(A + (size_t)row0 * DD);
            const float4* Rv = (const float4*)(res + (size_t)row0 * DD);
            float4* Hv = (float4*)(Hout + (size_t)row0 * DD);
            for (int i = tid; i < GTILE * DD / 4; i += 256) {
                int r = i >> 5;         // row in tile
                int kq = i & 31;        // k = 4*kq
                bool rowok = (row0 + r < n);
                float4 v = make_float4(0.f, 0.f, 0.f, 0.f);
                if (rowok) v = Av[i];
                if (fused) {
                    float4 rv = make_float4(0.f, 0.f, 0.f, 0.f);
                    if (rowok) rv = Rv[i];
                    int f4 = kq * 4;
                    v.x = fmaxf(v.x * s_scale[f4]     + s_shift[f4],     0.f) + rv.x;
                    v.y = fmaxf(v.y * s_scale[f4 + 1] + s_shift[f4 + 1], 0.f) + rv.y;
                    v.z = fmaxf(v.z * s_scale[f4 + 2] + s_shift[f4 + 2], 0.f) + rv.z;
                    v.w = fmaxf(v.w * s_scale[f4 + 3] + s_shift[f4 + 3], 0.f) + rv.w;
                    if (rowok) Hv[i] = v;
                }
                __half2 p0 = __floats2half2_rn(v.x, v.y);
                __half2 p1 = __floats2half2_rn(v.z, v.w);
                uint2 pk;
                pk.x = *(unsigned*)&p0;
                pk.y = *(unsigned*)&p1;
                int slot = ((r >> 4) * 4 + (kq >> 3)) * 64 +
                           (((kq >> 1) & 3) << 4) + (r & 15);
                int byte = slot * 16 + (kq & 1) * 8;
                byte ^= ((byte >> 9) & 7) << 4;
                *(uint2*)((char*)sA + byte) = pk;
            }
        }
        __syncthreads();

        f32x4 acc[8];
        #pragma unroll
        for (int cb = 0; cb < 8; cb++) acc[cb] = (f32x4)(0.0f);
        f16x8 af[4];
        #pragma unroll
        for (int ks = 0; ks < 4; ks++) {
            int rb = ((wave * 4 + ks) * 64 + lane) * 16;
            rb ^= ((rb >> 9) & 7) << 4;
            af[ks] = *(const f16x8*)((const char*)sA + rb);
        }
        #pragma unroll
        for (int cb = 0; cb < 8; cb++) {
            #pragma unroll
            for (int ks = 0; ks < 4; ks++) {
                f16x8 bf = *(const f16x8*)(sW + ((cb * 4 + ks) * 64 + lane) * 8);
                acc[cb] = __builtin_amdgcn_mfma_f32_16x16x32_f16(af[ks], bf,
                                                                 acc[cb], 0, 0, 0);
            }
        }

        // per-row dinv scale for the fp16 gather table
        float dv[4];
        #pragma unroll
        for (int rr = 0; rr < 4; rr++) {
            int row = row0 + wave * 16 + (lane >> 4) * 4 + rr;
            dv[rr] = (row < n) ? dscale[row] : 1.f;
        }

        // epilogue: acc -> per-wave LDS region (col-xor spreads banks) -> coalesced
        __half* sC = sA + wave * (16 * DD);
        #pragma unroll
        for (int cb = 0; cb < 8; cb++) {
            int col = cb * 16 + (lane & 15);
            #pragma unroll
            for (int rr = 0; rr < 4; rr++) {
                int grow = (lane >> 4) * 4 + rr;
                sC[grow * DD + (col ^ ((grow & 3) << 4))] =
                    __float2half(acc[cb][rr] * dv[rr]);
            }
        }
        __syncthreads();
        #pragma unroll
        for (int i2 = 0; i2 < 4; i2++) {
            int o = (i2 * 64 + lane) * 8;   // half index in wave's 16x128 region
            int grow = o >> 7;
            int col0 = o & 127;
            int row = row0 + wave * 16 + grow;
            if (row < n) {
                uint4 val = *(uint4*)(sC + grow * DD + (col0 ^ ((grow & 3) << 4)));
                *(uint4*)(C + (size_t)row * DD + col0) = val;
            }
        }
    }
}

// ---------------- aggregation: 16 lanes/node, 4-deep pipelined gather ------------
// Table hs = dinv[row]*h[row] (pre-scaled), so per-edge work is a pure fp16
// row add: o = di*(sum_s hs[s] + hs[node]) + bias.  4-deep explicit software
// pipeline keeps 4 row-loads in flight per lane (latency-bound gather fix).
#define ACC8(raw) { const __half2* hp_ = (const __half2*)&(raw);               \
    float2 c0_ = __half22float2(hp_[0]); float2 c1_ = __half22float2(hp_[1]);  \
    float2 c2_ = __half22float2(hp_[2]); float2 c3_ = __half22float2(hp_[3]);  \
    a[0] += c0_.x; a[1] += c0_.y; a[2] += c1_.x; a[3] += c1_.y;                \
    a[4] += c2_.x; a[5] += c2_.y; a[6] += c3_.x; a[7] += c3_.y; }

__global__ __launch_bounds__(256) void k_agg(const __half* __restrict__ h,
                                             const int* __restrict__ rowp,
                                             const unsigned* __restrict__ ev,
                                             const float* __restrict__ dinv,
                                             const float* __restrict__ bias,
                                             float* __restrict__ out,
                                             float* __restrict__ sums, int n) {
    int tid = threadIdx.x;
    int grp = tid >> 4;            // node within block 0..15
    int m = tid & 15;              // 16 B chunk within row
    int node = blockIdx.x * 16 + grp;
    bool activ = node < n;

    int beg = 0, end = 0;
    float di = 0.f;
    if (activ) { beg = rowp[node]; end = rowp[node + 1]; di = dinv[node]; }

    float sf[8] = {0.f, 0.f, 0.f, 0.f, 0.f, 0.f, 0.f, 0.f};
    float bf[8];
    {
        float4 b0 = *(const float4*)(bias + m * 8);
        float4 b1 = *(const float4*)(bias + m * 8 + 4);
        bf[0] = b0.x; bf[1] = b0.y; bf[2] = b0.z; bf[3] = b0.w;
        bf[4] = b1.x; bf[5] = b1.y; bf[6] = b1.z; bf[7] = b1.w;
        if (activ) {
            float4 raw = *(const float4*)(h + (size_t)node * DD + m * 8);
            const __half2* hp = (const __half2*)&raw;
            float2 s0 = __half22float2(hp[0]);
            float2 s1 = __half22float2(hp[1]);
            float2 s2 = __half22float2(hp[2]);
            float2 s3 = __half22float2(hp[3]);
            sf[0] = s0.x; sf[1] = s0.y; sf[2] = s1.x; sf[3] = s1.y;
            sf[4] = s2.x; sf[5] = s2.y; sf[6] = s3.x; sf[7] = s3.y;
        }
    }

    float a[8] = {0.f, 0.f, 0.f, 0.f, 0.f, 0.f, 0.f, 0.f};
    int e = beg;
    int cnt4 = (end - beg) >> 2;
    if (cnt4 > 0) {
        unsigned s0 = ev[e], s1 = ev[e + 1], s2 = ev[e + 2], s3 = ev[e + 3];
        float4 r0 = *(const float4*)(h + (size_t)s0 * DD + m * 8);
        float4 r1 = *(const float4*)(h + (size_t)s1 * DD + m * 8);
        float4 r2 = *(const float4*)(h + (size_t)s2 * DD + m * 8);
        float4 r3 = *(const float4*)(h + (size_t)s3 * DD + m * 8);
        for (int g = 1; g < cnt4; g++) {
            e += 4;
            unsigned t0 = ev[e], t1 = ev[e + 1], t2 = ev[e + 2], t3 = ev[e + 3];
            float4 q0 = *(const float4*)(h + (size_t)t0 * DD + m * 8);
            float4 q1 = *(const float4*)(h + (size_t)t1 * DD + m * 8);
            float4 q2 = *(const float4*)(h + (size_t)t2 * DD + m * 8);
            float4 q3 = *(const float4*)(h + (size_t)t3 * DD + m * 8);
            ACC8(r0); ACC8(r1); ACC8(r2); ACC8(r3);
            r0 = q0; r1 = q1; r2 = q2; r3 = q3;
        }
        ACC8(r0); ACC8(r1); ACC8(r2); ACC8(r3);
        e += 4;
    }
    for (; e < end; e++) {
        unsigned s = ev[e];
        float4 raw = *(const float4*)(h + (size_t)s * DD + m * 8);
        ACC8(raw);
    }

    float o[8];
    #pragma unroll
    for (int j = 0; j < 8; j++) o[j] = di * (a[j] + sf[j]) + bf[j];
    if (activ) {
        float* op = out + (size_t)node * DD + m * 8;
        *(float4*)op = make_float4(o[0], o[1], o[2], o[3]);
        *(float4*)(op + 4) = make_float4(o[4], o[5], o[6], o[7]);
    }

    __shared__ float rs[16][132];            // +4 pad breaks 128-stride conflicts
    #pragma unroll
    for (int j = 0; j < 8; j++) rs[grp][m * 8 + j] = activ ? o[j] : 0.f;
    __syncthreads();

    int bank = blockIdx.x & 15;
    if (tid < 128) {
        float s = 0.f;
        #pragma unroll
        for (int r2 = 0; r2 < 16; r2++) s += rs[r2][tid];
        atomicAdd(&sums[bank * 256 + tid], s);
    } else {
        int f = tid - 128;
        float q = 0.f;
        #pragma unroll
        for (int r2 = 0; r2 < 16; r2++) { float v = rs[r2][f]; q += v * v; }
        atomicAdd(&sums[bank * 256 + 128 + f], q);
    }
}

// ---------------- BN apply + ReLU + residual + fused attention score (layer 2) ----
__global__ __launch_bounds__(256) void k_bn(const float* __restrict__ X,
                                            const float* __restrict__ res,
                                            const float* __restrict__ sums,
                                            const float* __restrict__ gamma,
                                            const float* __restrict__ beta,
                                            const float* __restrict__ Wa,
                                            const float* __restrict__ ba,
                                            float* __restrict__ out,
                                            float* __restrict__ evec,
                                            float* __restrict__ Zb, int n) {
    __shared__ float s_scale[128], s_shift[128];
    if (threadIdx.x < 128) {
        int ff = threadIdx.x;
        float ssum = 0.f, qsum = 0.f;
        #pragma unroll
        for (int b = 0; b < 16; b++) {
            ssum += sums[b * 256 + ff];
            qsum += sums[b * 256 + 128 + ff];
        }
        float inv_n = 1.0f / (float)n;
        float mean = ssum * inv_n;
        float var = qsum * inv_n - mean * mean;
        float sc = gamma[ff] * (1.0f / sqrtf(var + BN_EPS));
        s_scale[ff] = sc;
        s_shift[ff] = beta[ff] - mean * sc;
    }
    __syncthreads();
    int idx = blockIdx.x * 256 + threadIdx.x;
    int total = n * (DD / 4);
    int f = (threadIdx.x & 31) * 4;
    float o[4] = {0.f, 0.f, 0.f, 0.f};
    if (idx < total) {
        float4 v = ((const float4*)X)[idx];
        float4 rv = ((const float4*)res)[idx];
        float vi[4] = {v.x, v.y, v.z, v.w};
        float ri[4] = {rv.x, rv.y, rv.z, rv.w};
        #pragma unroll
        for (int j = 0; j < 4; j++) {
            float x = vi[j] * s_scale[f + j] + s_shift[f + j];
            x = fmaxf(x, 0.f);
            o[j] = x + ri[j];
        }
        ((float4*)out)[idx] = make_float4(o[0], o[1], o[2], o[3]);
    }
    if (Wa != nullptr) {
        float t = 0.f;
        if (idx < total) {
            float4 wv = *(const float4*)(Wa + f);
            t = o[0] * wv.x + o[1] * wv.y + o[2] * wv.z + o[3] * wv.w;
        }
        #pragma unroll
        for (int m = 16; m >= 1; m >>= 1) t += __shfl_xor(t, m);
        __shared__ float part[8];
        if ((threadIdx.x & 31) == 0) {
            float ev = 0.f;
            if (idx < total) {
                ev = expf(tanhf(t + ba[0]));
                evec[idx >> 5] = ev;
            }
            part[threadIdx.x >> 5] = ev;
        }
        __syncthreads();
        if (threadIdx.x == 0) {
            float z = part[0] + part[1] + part[2] + part[3] +
                      part[4] + part[5] + part[6] + part[7];
            atomicAdd(&Zb[blockIdx.x & 63], z);
        }
    }
}

// ---------------- final: out = h * e / Z (Z from 64 banks) ----------------
__global__ __launch_bounds__(256) void k_out(const float* __restrict__ H,
                                             const float* __restrict__ evec,
                                             const float* __restrict__ Zb,
                                             float* __restrict__ out, int n) {
    __shared__ float sZ;
    if (threadIdx.x == 0) {
        float z = 0.f;
        #pragma unroll
        for (int i = 0; i < 64; i++) z += Zb[i];
        sZ = z;
    }
    __syncthreads();
    int idx = blockIdx.x * blockDim.x + threadIdx.x;
    int total = n * (DD / 4);
    if (idx >= total) return;
    int node = idx >> 5;
    float s = evec[node] / sZ;
    float4 h = ((const float4*)H)[idx];
    ((float4*)out)[idx] = make_float4(h.x * s, h.y * s, h.z * s, h.w * s);
}

extern "C" void kernel_launch(void* const* d_in, const int* in_sizes, int n_in,
                              void* d_out, int out_size, void* d_ws, size_t ws_size,
                              hipStream_t stream) {
    const float* x   = (const float*)d_in[0];
    const int* eidx  = (const int*)d_in[1];
    const float* W1  = (const float*)d_in[2];
    const float* b1  = (const float*)d_in[3];
    const float* g1  = (const float*)d_in[4];
    const float* be1 = (const float*)d_in[5];
    const float* W2  = (const float*)d_in[6];
    const float* b2  = (const float*)d_in[7];
    const float* g2  = (const float*)d_in[8];
    const float* be2 = (const float*)d_in[9];
    const float* Wa  = (const float*)d_in[10];
    const float* ba  = (const float*)d_in[11];
    float* out = (float*)d_out;

    const int* srcp = eidx;
    const int* dstp = eidx + NE;

    float* bufA = (float*)d_ws;              // N*D region; fp16 gather table
    float* bufB = bufA + (size_t)NN * DD;    // N*D (staging evS / agg out)
    float* bufC = bufB + (size_t)NN * DD;    // N*D (h1 / h2)
    unsigned* ev = (unsigned*)(bufC + (size_t)NN * DD);   // NE 4B records (src)
    float* dinv = (float*)(ev + NE);         // NN
    float* evec = dinv + NN;                 // NN
    float* sums = evec + NN;                 // 2 layers x 16 banks x 256 = 8192
    float* Zb   = sums + 8192;               // 64 banks
    int* cnt    = (int*)(Zb + 64);           // NN
    int* rowp   = cnt + NN;                  // NN+1 (pad 64)
    int* cursor = rowp + NN + 64;            // NN
    int* bsum   = cursor + NN;               // 256
    int* bucketCur = bsum + 256;             // NBUCK (pad 256)
    __half* Wf  = (__half*)(bucketCur + 256);// 2 x DD*DD fp16 fragment tables

    __half* hH  = (__half*)bufA;             // fp16 gather table, 12.8 MB
    unsigned* evS = (unsigned*)bufB;         // staged 4B records, 3.2 MB (aliased)

    float* sumsL1 = sums;
    float* sumsL2 = sums + 4096;

    const int nscan = (NN + 255) / 256;      // 196 blocks

    // ---- W fragment prep ----
    k_wprep<<<16, 256, 0, stream>>>(W1, W2, Wf);

    // ---- CSR build (k_rowp block 0 zeroes sums+Zb) ----
    hipMemsetAsync(cnt, 0, (size_t)NN * sizeof(int), stream);
    k_hist<<<(NE + 255) / 256, 256, 0, stream>>>(dstp, cnt, NE);
    k_bsum<<<nscan, 256, 0, stream>>>(cnt, bsum, NN);
    k_bscan<<<1, 256, 0, stream>>>(bsum, nscan);
    k_rowp<<<nscan, 256, 0, stream>>>(cnt, bsum, rowp, cursor, bucketCur, dinv,
                                      sums, NN);
    k_binA<<<(NE + TILE_A - 1) / TILE_A, 256, 0, stream>>>(srcp, dstp,
                                                           bucketCur, evS, NE);
    k_binB<<<NBUCK, 256, 0, stream>>>(evS, rowp, cursor, ev, NN);

    int gemm_grid = (NN + GTILE - 1) / GTILE;        // 782
    int agg_grid  = (NN + 15) / 16;                  // 3125
    int ew_grid   = (NN * (DD / 4) + 255) / 256;     // 6250

    // ---- layer 1 (plain GEMM from x; table scaled by dinv) ----
    k_gemm<<<gemm_grid, 256, 0, stream>>>(x, nullptr, nullptr, nullptr, nullptr,
                                          nullptr, dinv, Wf, hH, NN);
    k_agg<<<agg_grid, 256, 0, stream>>>(hH, rowp, ev, dinv, b1, bufB, sumsL1, NN);

    // ---- layer 2 (BN1+ReLU+residual fused into GEMM2 staging; h1 -> bufC) ----
    k_gemm<<<gemm_grid, 256, 0, stream>>>(bufB, x, sumsL1, g1, be1, bufC,
                                          dinv, Wf + (size_t)DD * DD, hH, NN);
    k_agg<<<agg_grid, 256, 0, stream>>>(hH, rowp, ev, dinv, b2, bufB, sumsL2, NN);
    k_bn<<<ew_grid, 256, 0, stream>>>(bufB, bufC, sumsL2, g2, be2, Wa, ba,
                                      bufC, evec, Zb, NN);   // in-place res ok

    // ---- output ----
    k_out<<<ew_grid, 256, 0, stream>>>(bufC, evec, Zb, out, NN);
}

// Round 7
// 273.333 us; speedup vs baseline: 1.1712x; 1.1557x over previous
//
#include <hip/hip_runtime.h>
#include <hip/hip_fp16.h>

#define NN 50000
#define DD 128
#define NE 800000
#define BN_EPS 1e-5f
#define NBUCK 196           // ceil(NN/256): bucket = dst>>8, 256 nodes per bucket
#define TILE_A 4096         // edges per k_binA2 block

typedef _Float16 f16x8 __attribute__((ext_vector_type(8)));
typedef float f32x4 __attribute__((ext_vector_type(4)));

// ---------------- phase A1: global bucket histogram (replaces k_hist chain) ------
__global__ __launch_bounds__(256) void k_binA1(const int* __restrict__ dst,
                                               int* __restrict__ bucketCnt, int ne) {
    __shared__ int hcnt[NBUCK];
    int tid = threadIdx.x;
    for (int i = tid; i < NBUCK; i += 256) hcnt[i] = 0;
    __syncthreads();
    int base = blockIdx.x * TILE_A;
    int lim = ne - base;
    if (lim > TILE_A) lim = TILE_A;
    for (int i = tid; i < lim; i += 256) atomicAdd(&hcnt[dst[base + i] >> 8], 1);
    __syncthreads();
    for (int b = tid; b < NBUCK; b += 256)
        if (hcnt[b]) atomicAdd(&bucketCnt[b], hcnt[b]);
}

// ---------------- phase A2: scatter into bucket-contiguous staging ---------------
// Each block computes the 196-entry exclusive scan of bucketCnt locally (cheap,
// no scan kernel), reserves per-bucket runs via bucketRes atomics, rank-scatters.
// 4 B record: src (16 b) | dst-within-bucket (8 b).
__global__ __launch_bounds__(256) void k_binA2(const int* __restrict__ src,
                                               const int* __restrict__ dst,
                                               const int* __restrict__ bucketCnt,
                                               int* __restrict__ bucketRes,
                                               unsigned* __restrict__ evS, int ne) {
    __shared__ int sc[256];
    __shared__ int sExcl[256];
    __shared__ int hcnt[NBUCK];
    __shared__ int hbase[NBUCK];
    int tid = threadIdx.x;
    int v = (tid < NBUCK) ? bucketCnt[tid] : 0;
    sc[tid] = v;
    __syncthreads();
    for (int off = 1; off < 256; off <<= 1) {
        int add = (tid >= off) ? sc[tid - off] : 0;
        __syncthreads();
        sc[tid] += add;
        __syncthreads();
    }
    sExcl[tid] = sc[tid] - v;
    for (int i = tid; i < NBUCK; i += 256) hcnt[i] = 0;
    __syncthreads();

    int base = blockIdx.x * TILE_A;
    int lim = ne - base;
    if (lim > TILE_A) lim = TILE_A;
    for (int i = tid; i < lim; i += 256) atomicAdd(&hcnt[dst[base + i] >> 8], 1);
    __syncthreads();
    for (int b = tid; b < NBUCK; b += 256) {
        hbase[b] = hcnt[b] ? (sExcl[b] + atomicAdd(&bucketRes[b], hcnt[b])) : 0;
        hcnt[b] = 0;
    }
    __syncthreads();
    for (int i = tid; i < lim; i += 256) {
        int d = dst[base + i];
        int s = src[base + i];
        int bk = d >> 8;
        int rank = atomicAdd(&hcnt[bk], 1);
        evS[hbase[bk] + rank] = (unsigned)s | ((unsigned)(d & 255) << 16);
    }
}

// ---------------- phase B: per-bucket counting sort -> ev, rowp, dinv ------------
// One block per bucket.  Produces the per-node CSR (rowp/dinv) as a byproduct
// of the in-block 256-bin sort — the old hist/bsum/bscan/rowp chain is gone.
__global__ __launch_bounds__(256) void k_binB(const unsigned* __restrict__ evS,
                                              const int* __restrict__ bucketCnt,
                                              unsigned* __restrict__ ev,
                                              int* __restrict__ rowp,
                                              float* __restrict__ dinv, int n) {
    __shared__ int sc[256];
    __shared__ int ncnt[256];
    __shared__ int nbase[256];
    __shared__ int ncur[256];
    int tid = threadIdx.x;
    int b = blockIdx.x;

    int v = (tid < NBUCK) ? bucketCnt[tid] : 0;
    sc[tid] = v;
    __syncthreads();
    for (int off = 1; off < 256; off <<= 1) {
        int add = (tid >= off) ? sc[tid - off] : 0;
        __syncthreads();
        sc[tid] += add;
        __syncthreads();
    }
    int lo = sc[b] - ((b < NBUCK) ? bucketCnt[b] : 0);   // exclusive base
    int cnt_b = bucketCnt[b];

    ncnt[tid] = 0;
    __syncthreads();
    for (int p = tid; p < cnt_b; p += 256)
        atomicAdd(&ncnt[evS[lo + p] >> 16], 1);
    __syncthreads();
    int nv = ncnt[tid];
    sc[tid] = nv;
    __syncthreads();
    for (int off = 1; off < 256; off <<= 1) {
        int add = (tid >= off) ? sc[tid - off] : 0;
        __syncthreads();
        sc[tid] += add;
        __syncthreads();
    }
    nbase[tid] = sc[tid] - nv;
    ncur[tid] = sc[tid] - nv;
    int node0 = b << 8;
    int node = node0 + tid;
    if (node < n) {
        rowp[node] = lo + nbase[tid];
        dinv[node] = 1.0f / sqrtf((float)(nv + 1));
    }
    if (b == NBUCK - 1 && tid == 0) rowp[n] = lo + cnt_b;
    __syncthreads();
    for (int p = tid; p < cnt_b; p += 256) {
        unsigned r = evS[lo + p];
        int ln = r >> 16;
        int rank = atomicAdd(&ncur[ln], 1);
        ev[lo + rank] = r & 0xFFFFu;
    }
}

// ---------------- GEMM: MFMA fp16, inline W conversion, fused BN prologue --------
// Tile 64 rows x 128 cols, K=128.  4 waves, wave w owns rows [16w,16w+16).
// W fp32 -> fp16 B-fragments converted in-kernel (k_wprep eliminated).
// fp16 C table is scaled by dscale[row] (= dinv) so k_agg needs no edge weight.
// If res != nullptr: A-input is BN(Araw)+ReLU+res (layer-1 epilogue fused into
// layer-2 staging); fp32 (unscaled) result also goes to Hout.
#define GTILE 64
__global__ __launch_bounds__(256) void k_gemm(const float* __restrict__ A,
                                              const float* __restrict__ res,
                                              const float* __restrict__ sums,
                                              const float* __restrict__ gamma,
                                              const float* __restrict__ beta,
                                              float* __restrict__ Hout,
                                              const float* __restrict__ dscale,
                                              const float* __restrict__ W,
                                              __half* __restrict__ C, int n) {
    __shared__ __half sW[DD * DD];       // 32 KB fragment-linear (no swizzle)
    __shared__ __half sA[GTILE * DD];    // 16 KB fragment-linear (swizzled)
    __shared__ float s_scale[DD], s_shift[DD];
    int tid = threadIdx.x;
    int wave = tid >> 6;
    int lane = tid & 63;
    bool fused = (res != nullptr);

    {   // stage W: fp32 -> fp16 B-fragment layout, in-kernel
        for (int s = tid; s < DD * DD / 8; s += 256) {
            int l = s & 63;
            int ks = (s >> 6) & 3;
            int cb = s >> 8;
            int col = cb * 16 + (l & 15);
            int kbase = ks * 32 + (l >> 4) * 8;
            __align__(16) __half tmp[8];
            #pragma unroll
            for (int j = 0; j < 8; j++)
                tmp[j] = __float2half_rn(W[(kbase + j) * DD + col]);
            *(uint4*)(sW + s * 8) = *(uint4*)tmp;
        }
    }
    if (fused && tid < DD) {
        float ssum = 0.f, qsum = 0.f;
        #pragma unroll
        for (int b = 0; b < 16; b++) {
            ssum += sums[b * 256 + tid];
            qsum += sums[b * 256 + 128 + tid];
        }
        float inv_n = 1.0f / (float)n;
        float mean = ssum * inv_n;
        float var = qsum * inv_n - mean * mean;
        float sc = gamma[tid] * (1.0f / sqrtf(var + BN_EPS));
        s_scale[tid] = sc;
        s_shift[tid] = beta[tid] - mean * sc;
    }

    int ntiles = (n + GTILE - 1) / GTILE;
    for (int t = blockIdx.x; t < ntiles; t += gridDim.x) {
        int row0 = t * GTILE;
        __syncthreads();   // covers W/stats stage (1st iter) + prev-tile reads
        {   // stage A tile: (optional BN+ReLU+res) fp32 -> fp16 fragments, swizzled
            const float4* Av = (const float4*)(A + (size_t)row0 * DD);
            const float4* Rv = (const float4*)(res + (size_t)row0 * DD);
            float4* Hv = (float4*)(Hout + (size_t)row0 * DD);
            for (int i = tid; i < GTILE * DD / 4; i += 256) {
                int r = i >> 5;         // row in tile
                int kq = i & 31;        // k = 4*kq
                bool rowok = (row0 + r < n);
                float4 v = make_float4(0.f, 0.f, 0.f, 0.f);
                if (rowok) v = Av[i];
                if (fused) {
                    float4 rv = make_float4(0.f, 0.f, 0.f, 0.f);
                    if (rowok) rv = Rv[i];
                    int f4 = kq * 4;
                    v.x = fmaxf(v.x * s_scale[f4]     + s_shift[f4],     0.f) + rv.x;
                    v.y = fmaxf(v.y * s_scale[f4 + 1] + s_shift[f4 + 1], 0.f) + rv.y;
                    v.z = fmaxf(v.z * s_scale[f4 + 2] + s_shift[f4 + 2], 0.f) + rv.z;
                    v.w = fmaxf(v.w * s_scale[f4 + 3] + s_shift[f4 + 3], 0.f) + rv.w;
                    if (rowok) Hv[i] = v;
                }
                __half2 p0 = __floats2half2_rn(v.x, v.y);
                __half2 p1 = __floats2half2_rn(v.z, v.w);
                uint2 pk;
                pk.x = *(unsigned*)&p0;
                pk.y = *(unsigned*)&p1;
                int slot = ((r >> 4) * 4 + (kq >> 3)) * 64 +
                           (((kq >> 1) & 3) << 4) + (r & 15);
                int byte = slot * 16 + (kq & 1) * 8;
                byte ^= ((byte >> 9) & 7) << 4;
                *(uint2*)((char*)sA + byte) = pk;
            }
        }
        __syncthreads();

        f32x4 acc[8];
        #pragma unroll
        for (int cb = 0; cb < 8; cb++) acc[cb] = (f32x4)(0.0f);
        f16x8 af[4];
        #pragma unroll
        for (int ks = 0; ks < 4; ks++) {
            int rb = ((wave * 4 + ks) * 64 + lane) * 16;
            rb ^= ((rb >> 9) & 7) << 4;
            af[ks] = *(const f16x8*)((const char*)sA + rb);
        }
        #pragma unroll
        for (int cb = 0; cb < 8; cb++) {
            #pragma unroll
            for (int ks = 0; ks < 4; ks++) {
                f16x8 bf = *(const f16x8*)(sW + ((cb * 4 + ks) * 64 + lane) * 8);
                acc[cb] = __builtin_amdgcn_mfma_f32_16x16x32_f16(af[ks], bf,
                                                                 acc[cb], 0, 0, 0);
            }
        }

        // RACE FIX: epilogue below writes sC inside sA, but wave w's sC region
        // (4 KB stride) lands inside OTHER waves' af fragment regions (16 KB
        // stride).  Barrier guarantees all waves' af ds_reads retired before
        // any wave overwrites the staging buffer.  (Caused rare post-replay
        // divergence: fast wave's epilogue corrupted slow wave's A operand.)
        __syncthreads();

        // per-row dinv scale for the fp16 gather table
        float dv[4];
        #pragma unroll
        for (int rr = 0; rr < 4; rr++) {
            int row = row0 + wave * 16 + (lane >> 4) * 4 + rr;
            dv[rr] = (row < n) ? dscale[row] : 1.f;
        }

        // epilogue: acc -> per-wave LDS region (col-xor spreads banks) -> coalesced
        __half* sC = sA + wave * (16 * DD);
        #pragma unroll
        for (int cb = 0; cb < 8; cb++) {
            int col = cb * 16 + (lane & 15);
            #pragma unroll
            for (int rr = 0; rr < 4; rr++) {
                int grow = (lane >> 4) * 4 + rr;
                sC[grow * DD + (col ^ ((grow & 3) << 4))] =
                    __float2half(acc[cb][rr] * dv[rr]);
            }
        }
        __syncthreads();
        #pragma unroll
        for (int i2 = 0; i2 < 4; i2++) {
            int o = (i2 * 64 + lane) * 8;   // half index in wave's 16x128 region
            int grow = o >> 7;
            int col0 = o & 127;
            int row = row0 + wave * 16 + grow;
            if (row < n) {
                uint4 val = *(uint4*)(sC + grow * DD + (col0 ^ ((grow & 3) << 4)));
                *(uint4*)(C + (size_t)row * DD + col0) = val;
            }
        }
    }
}

// ---------------- aggregation: 16 lanes/node, 4-deep pipelined gather ------------
#define ACC8(raw) { const __half2* hp_ = (const __half2*)&(raw);               \
    float2 c0_ = __half22float2(hp_[0]); float2 c1_ = __half22float2(hp_[1]);  \
    float2 c2_ = __half22float2(hp_[2]); float2 c3_ = __half22float2(hp_[3]);  \
    a[0] += c0_.x; a[1] += c0_.y; a[2] += c1_.x; a[3] += c1_.y;                \
    a[4] += c2_.x; a[5] += c2_.y; a[6] += c3_.x; a[7] += c3_.y; }

__global__ __launch_bounds__(256) void k_agg(const __half* __restrict__ h,
                                             const int* __restrict__ rowp,
                                             const unsigned* __restrict__ ev,
                                             const float* __restrict__ dinv,
                                             const float* __restrict__ bias,
                                             float* __restrict__ out,
                                             float* __restrict__ sums, int n) {
    int tid = threadIdx.x;
    int grp = tid >> 4;            // node within block 0..15
    int m = tid & 15;              // 16 B chunk within row
    int node = blockIdx.x * 16 + grp;
    bool activ = node < n;

    int beg = 0, end = 0;
    float di = 0.f;
    if (activ) { beg = rowp[node]; end = rowp[node + 1]; di = dinv[node]; }

    float sf[8] = {0.f, 0.f, 0.f, 0.f, 0.f, 0.f, 0.f, 0.f};
    float bf[8];
    {
        float4 b0 = *(const float4*)(bias + m * 8);
        float4 b1 = *(const float4*)(bias + m * 8 + 4);
        bf[0] = b0.x; bf[1] = b0.y; bf[2] = b0.z; bf[3] = b0.w;
        bf[4] = b1.x; bf[5] = b1.y; bf[6] = b1.z; bf[7] = b1.w;
        if (activ) {
            float4 raw = *(const float4*)(h + (size_t)node * DD + m * 8);
            const __half2* hp = (const __half2*)&raw;
            float2 s0 = __half22float2(hp[0]);
            float2 s1 = __half22float2(hp[1]);
            float2 s2 = __half22float2(hp[2]);
            float2 s3 = __half22float2(hp[3]);
            sf[0] = s0.x; sf[1] = s0.y; sf[2] = s1.x; sf[3] = s1.y;
            sf[4] = s2.x; sf[5] = s2.y; sf[6] = s3.x; sf[7] = s3.y;
        }
    }

    float a[8] = {0.f, 0.f, 0.f, 0.f, 0.f, 0.f, 0.f, 0.f};
    int e = beg;
    int cnt4 = (end - beg) >> 2;
    if (cnt4 > 0) {
        unsigned s0 = ev[e], s1 = ev[e + 1], s2 = ev[e + 2], s3 = ev[e + 3];
        float4 r0 = *(const float4*)(h + (size_t)s0 * DD + m * 8);
        float4 r1 = *(const float4*)(h + (size_t)s1 * DD + m * 8);
        float4 r2 = *(const float4*)(h + (size_t)s2 * DD + m * 8);
        float4 r3 = *(const float4*)(h + (size_t)s3 * DD + m * 8);
        for (int g = 1; g < cnt4; g++) {
            e += 4;
            unsigned t0 = ev[e], t1 = ev[e + 1], t2 = ev[e + 2], t3 = ev[e + 3];
            float4 q0 = *(const float4*)(h + (size_t)t0 * DD + m * 8);
            float4 q1 = *(const float4*)(h + (size_t)t1 * DD + m * 8);
            float4 q2 = *(const float4*)(h + (size_t)t2 * DD + m * 8);
            float4 q3 = *(const float4*)(h + (size_t)t3 * DD + m * 8);
            ACC8(r0); ACC8(r1); ACC8(r2); ACC8(r3);
            r0 = q0; r1 = q1; r2 = q2; r3 = q3;
        }
        ACC8(r0); ACC8(r1); ACC8(r2); ACC8(r3);
        e += 4;
    }
    for (; e < end; e++) {
        unsigned s = ev[e];
        float4 raw = *(const float4*)(h + (size_t)s * DD + m * 8);
        ACC8(raw);
    }

    float o[8];
    #pragma unroll
    for (int j = 0; j < 8; j++) o[j] = di * (a[j] + sf[j]) + bf[j];
    if (activ) {
        float* op = out + (size_t)node * DD + m * 8;
        *(float4*)op = make_float4(o[0], o[1], o[2], o[3]);
        *(float4*)(op + 4) = make_float4(o[4], o[5], o[6], o[7]);
    }

    __shared__ float rs[16][132];            // +4 pad breaks 128-stride conflicts
    #pragma unroll
    for (int j = 0; j < 8; j++) rs[grp][m * 8 + j] = activ ? o[j] : 0.f;
    __syncthreads();

    int bank = blockIdx.x & 15;
    if (tid < 128) {
        float s = 0.f;
        #pragma unroll
        for (int r2 = 0; r2 < 16; r2++) s += rs[r2][tid];
        atomicAdd(&sums[bank * 256 + tid], s);
    } else {
        int f = tid - 128;
        float q = 0.f;
        #pragma unroll
        for (int r2 = 0; r2 < 16; r2++) { float v = rs[r2][f]; q += v * v; }
        atomicAdd(&sums[bank * 256 + 128 + f], q);
    }
}

// ---------------- BN apply + ReLU + residual + fused attention score (layer 2) ----
__global__ __launch_bounds__(256) void k_bn(const float* __restrict__ X,
                                            const float* __restrict__ res,
                                            const float* __restrict__ sums,
                                            const float* __restrict__ gamma,
                                            const float* __restrict__ beta,
                                            const float* __restrict__ Wa,
                                            const float* __restrict__ ba,
                                            float* __restrict__ out,
                                            float* __restrict__ evec,
                                            float* __restrict__ Zb, int n) {
    __shared__ float s_scale[128], s_shift[128];
    if (threadIdx.x < 128) {
        int ff = threadIdx.x;
        float ssum = 0.f, qsum = 0.f;
        #pragma unroll
        for (int b = 0; b < 16; b++) {
            ssum += sums[b * 256 + ff];
            qsum += sums[b * 256 + 128 + ff];
        }
        float inv_n = 1.0f / (float)n;
        float mean = ssum * inv_n;
        float var = qsum * inv_n - mean * mean;
        float sc = gamma[ff] * (1.0f / sqrtf(var + BN_EPS));
        s_scale[ff] = sc;
        s_shift[ff] = beta[ff] - mean * sc;
    }
    __syncthreads();
    int idx = blockIdx.x * 256 + threadIdx.x;
    int total = n * (DD / 4);
    int f = (threadIdx.x & 31) * 4;
    float o[4] = {0.f, 0.f, 0.f, 0.f};
    if (idx < total) {
        float4 v = ((const float4*)X)[idx];
        float4 rv = ((const float4*)res)[idx];
        float vi[4] = {v.x, v.y, v.z, v.w};
        float ri[4] = {rv.x, rv.y, rv.z, rv.w};
        #pragma unroll
        for (int j = 0; j < 4; j++) {
            float x = vi[j] * s_scale[f + j] + s_shift[f + j];
            x = fmaxf(x, 0.f);
            o[j] = x + ri[j];
        }
        ((float4*)out)[idx] = make_float4(o[0], o[1], o[2], o[3]);
    }
    if (Wa != nullptr) {
        float t = 0.f;
        if (idx < total) {
            float4 wv = *(const float4*)(Wa + f);
            t = o[0] * wv.x + o[1] * wv.y + o[2] * wv.z + o[3] * wv.w;
        }
        #pragma unroll
        for (int m = 16; m >= 1; m >>= 1) t += __shfl_xor(t, m);
        __shared__ float part[8];
        if ((threadIdx.x & 31) == 0) {
            float ev = 0.f;
            if (idx < total) {
                ev = expf(tanhf(t + ba[0]));
                evec[idx >> 5] = ev;
            }
            part[threadIdx.x >> 5] = ev;
        }
        __syncthreads();
        if (threadIdx.x == 0) {
            float z = part[0] + part[1] + part[2] + part[3] +
                      part[4] + part[5] + part[6] + part[7];
            atomicAdd(&Zb[blockIdx.x & 63], z);
        }
    }
}

// ---------------- final: out = h * e / Z (Z from 64 banks) ----------------
__global__ __launch_bounds__(256) void k_out(const float* __restrict__ H,
                                             const float* __restrict__ evec,
                                             const float* __restrict__ Zb,
                                             float* __restrict__ out, int n) {
    __shared__ float sZ;
    if (threadIdx.x == 0) {
        float z = 0.f;
        #pragma unroll
        for (int i = 0; i < 64; i++) z += Zb[i];
        sZ = z;
    }
    __syncthreads();
    int idx = blockIdx.x * blockDim.x + threadIdx.x;
    int total = n * (DD / 4);
    if (idx >= total) return;
    int node = idx >> 5;
    float s = evec[node] / sZ;
    float4 h = ((const float4*)H)[idx];
    ((float4*)out)[idx] = make_float4(h.x * s, h.y * s, h.z * s, h.w * s);
}

extern "C" void kernel_launch(void* const* d_in, const int* in_sizes, int n_in,
                              void* d_out, int out_size, void* d_ws, size_t ws_size,
                              hipStream_t stream) {
    const float* x   = (const float*)d_in[0];
    const int* eidx  = (const int*)d_in[1];
    const float* W1  = (const float*)d_in[2];
    const float* b1  = (const float*)d_in[3];
    const float* g1  = (const float*)d_in[4];
    const float* be1 = (const float*)d_in[5];
    const float* W2  = (const float*)d_in[6];
    const float* b2  = (const float*)d_in[7];
    const float* g2  = (const float*)d_in[8];
    const float* be2 = (const float*)d_in[9];
    const float* Wa  = (const float*)d_in[10];
    const float* ba  = (const float*)d_in[11];
    float* out = (float*)d_out;

    const int* srcp = eidx;
    const int* dstp = eidx + NE;

    float* bufA = (float*)d_ws;              // N*D region; fp16 gather table
    float* bufB = bufA + (size_t)NN * DD;    // N*D (staging evS / agg out)
    float* bufC = bufB + (size_t)NN * DD;    // N*D (h1 / h2)
    unsigned* ev = (unsigned*)(bufC + (size_t)NN * DD);   // NE 4B records (src)
    float* dinv = (float*)(ev + NE);         // NN
    float* evec = dinv + NN;                 // NN
    // zeroed region (one memset): bucketCnt(256) | bucketRes(256) | sums(8192) | Zb(64)
    int* bucketCnt = (int*)(evec + NN);      // 256 (NBUCK used)
    int* bucketRes = bucketCnt + 256;        // 256
    float* sums = (float*)(bucketRes + 256); // 2 layers x 16 banks x 256 = 8192
    float* Zb   = sums + 8192;               // 64 banks
    int* rowp   = (int*)(Zb + 64);           // NN+1 (pad 64)

    __half* hH  = (__half*)bufA;             // fp16 gather table, 12.8 MB
    unsigned* evS = (unsigned*)bufB;         // staged 4B records, 3.2 MB (aliased)

    float* sumsL1 = sums;
    float* sumsL2 = sums + 4096;

    // ---- CSR build: 1 memset + 3 kernels (was 1 memset + 6 kernels) ----
    hipMemsetAsync(bucketCnt, 0, (size_t)(256 + 256 + 8192 + 64) * sizeof(int),
                   stream);
    const int nA = (NE + TILE_A - 1) / TILE_A;       // 196
    k_binA1<<<nA, 256, 0, stream>>>(dstp, bucketCnt, NE);
    k_binA2<<<nA, 256, 0, stream>>>(srcp, dstp, bucketCnt, bucketRes, evS, NE);
    k_binB<<<NBUCK, 256, 0, stream>>>(evS, bucketCnt, ev, rowp, dinv, NN);

    int gemm_grid = (NN + GTILE - 1) / GTILE;        // 782
    int agg_grid  = (NN + 15) / 16;                  // 3125
    int ew_grid   = (NN * (DD / 4) + 255) / 256;     // 6250

    // ---- layer 1 (GEMM from x; table scaled by dinv; W converted in-kernel) ----
    k_gemm<<<gemm_grid, 256, 0, stream>>>(x, nullptr, nullptr, nullptr, nullptr,
                                          nullptr, dinv, W1, hH, NN);
    k_agg<<<agg_grid, 256, 0, stream>>>(hH, rowp, ev, dinv, b1, bufB, sumsL1, NN);

    // ---- layer 2 (BN1+ReLU+residual fused into GEMM2 staging; h1 -> bufC) ----
    k_gemm<<<gemm_grid, 256, 0, stream>>>(bufB, x, sumsL1, g1, be1, bufC,
                                          dinv, W2, hH, NN);
    k_agg<<<agg_grid, 256, 0, stream>>>(hH, rowp, ev, dinv, b2, bufB, sumsL2, NN);
    k_bn<<<ew_grid, 256, 0, stream>>>(bufB, bufC, sumsL2, g2, be2, Wa, ba,
                                      bufC, evec, Zb, NN);   // in-place res ok

    // ---- output ----
    k_out<<<ew_grid, 256, 0, stream>>>(bufC, evec, Zb, out, NN);
}